// Round 1
// baseline (7309.617 us; speedup 1.0000x reference)
//
#include <hip/hip_runtime.h>
#include <math.h>

#define BB 8
#define TT 12
#define HH 128
#define WW 128
#define FF 64
#define GG 256   // 4*FF
#define PRED_LEN 6

#define TW 64    // pixels per block along W
#define KPX 16   // pixels per thread (per wave: 16 px, 64 features)

__device__ __forceinline__ float sigf(float x) { return 1.f / (1.f + __expf(-x)); }
__device__ __forceinline__ float tanhfast(float x) { return 1.f - 2.f / (__expf(2.f * x) + 1.f); }

// Fused ConvLSTM step: z = conv3x3(x_t,Wk) + conv3x3(h,Wr) + b; gates; update c,h.
// block 256 = 4 waves; wave p handles pixels [x0+p*16, x0+p*16+16), lane = feature f0.
__global__ __launch_bounds__(256) void lstm_step(
    const float* __restrict__ x,     // (B,T,H,W,1)
    int t,
    const float* __restrict__ h_in,  // (B,H,W,F)
    float* c_buf,                    // (B,H,W,F) in/out (pointwise, in-place safe)
    float* __restrict__ h_out,       // (B,H,W,F)
    const float* __restrict__ wk,    // (3,3,1,4F)
    const float* __restrict__ wr,    // (3,3,F,4F)
    const float* __restrict__ bias)  // (4F)
{
    __shared__ float sh[3][TW + 2][FF];
    __shared__ float sx[3][TW + 2];

    const int tid = threadIdx.x;
    const int x0 = blockIdx.x * TW;
    const int y  = blockIdx.y;
    const int b  = blockIdx.z;

    // ---- stage h tile (3 rows x 66 cols x 64 ci), zero-padded ----
    const int NH = 3 * (TW + 2) * FF;
    for (int i = tid; i < NH; i += 256) {
        int ci  = i & (FF - 1);
        int rc  = i >> 6;
        int col = rc % (TW + 2);
        int r   = rc / (TW + 2);
        int gy = y + r - 1, gx = x0 + col - 1;
        float v = 0.f;
        if ((unsigned)gy < HH && (unsigned)gx < WW)
            v = h_in[(((size_t)b * HH + gy) * WW + gx) * FF + ci];
        sh[r][col][ci] = v;
    }
    // ---- stage x tile ----
    for (int i = tid; i < 3 * (TW + 2); i += 256) {
        int col = i % (TW + 2);
        int r   = i / (TW + 2);
        int gy = y + r - 1, gx = x0 + col - 1;
        float v = 0.f;
        if ((unsigned)gy < HH && (unsigned)gx < WW)
            v = x[((((size_t)b * TT + t) * HH + gy) * WW + gx)];
        sx[r][col] = v;
    }
    __syncthreads();

    const int f0 = tid & 63;
    const int p  = tid >> 6;   // wave id
    const int xb = p * KPX;

    float acc[4][KPX];
    #pragma unroll
    for (int q = 0; q < 4; ++q) {
        float bq = bias[q * 64 + f0];
        #pragma unroll
        for (int k = 0; k < KPX; ++k) acc[q][k] = bq;
    }

    // ---- input conv (Cin = 1) ----
    #pragma unroll
    for (int dy = 0; dy < 3; ++dy) {
        #pragma unroll
        for (int dx = 0; dx < 3; ++dx) {
            const float* kp = wk + (dy * 3 + dx) * GG + f0;
            float kw0 = kp[0], kw1 = kp[64], kw2 = kp[128], kw3 = kp[192];
            #pragma unroll
            for (int k = 0; k < KPX; ++k) {
                float xv = sx[dy][xb + k + dx];
                acc[0][k] = fmaf(xv, kw0, acc[0][k]);
                acc[1][k] = fmaf(xv, kw1, acc[1][k]);
                acc[2][k] = fmaf(xv, kw2, acc[2][k]);
                acc[3][k] = fmaf(xv, kw3, acc[3][k]);
            }
        }
    }

    // ---- recurrent conv ----
    for (int dy = 0; dy < 3; ++dy) {
        for (int dx = 0; dx < 3; ++dx) {
            const float* wp = wr + (size_t)(dy * 3 + dx) * FF * GG + f0;
            const float* shp = &sh[dy][xb + dx][0];
            #pragma unroll 2
            for (int c4 = 0; c4 < FF / 4; ++c4) {
                float w[4][4];
                #pragma unroll
                for (int j = 0; j < 4; ++j) {
                    const float* wq = wp + (c4 * 4 + j) * GG;
                    w[j][0] = wq[0];
                    w[j][1] = wq[64];
                    w[j][2] = wq[128];
                    w[j][3] = wq[192];
                }
                #pragma unroll
                for (int k = 0; k < KPX; ++k) {
                    const float4 hv = *(const float4*)(shp + k * FF + c4 * 4);
                    float hva[4] = {hv.x, hv.y, hv.z, hv.w};
                    #pragma unroll
                    for (int j = 0; j < 4; ++j) {
                        #pragma unroll
                        for (int q = 0; q < 4; ++q)
                            acc[q][k] = fmaf(hva[j], w[j][q], acc[q][k]);
                    }
                }
            }
        }
    }

    // ---- gates + cell update (Keras order i,f,g,o) ----
    #pragma unroll
    for (int k = 0; k < KPX; ++k) {
        int gx = x0 + xb + k;
        size_t idx = (((size_t)b * HH + y) * WW + gx) * FF + f0;
        float cp = c_buf[idx];
        float iv = sigf(acc[0][k]);
        float fv = sigf(acc[1][k]);
        float gv = tanhfast(acc[2][k]);
        float ov = sigf(acc[3][k]);
        float cn = fv * cp + iv * gv;
        float hn = ov * tanhfast(cn);
        c_buf[idx] = cn;
        h_out[idx] = hn;
    }
}

// pred = sigmoid(conv3x3(cur, w_out) + b_out): (B,H,W,64) -> (B,H,W,1)
// block 256 = 32 pixels; 8 lanes per pixel, each lane 8 input channels.
__global__ __launch_bounds__(256) void dec_conv(
    const float* __restrict__ cur, const float* __restrict__ w_out,
    const float* __restrict__ b_out, float* __restrict__ out, int ti)
{
    int tid = threadIdx.x;
    int j  = tid & 7;
    int pp = tid >> 3;              // 0..31
    int xx = blockIdx.x * 32 + pp;
    int y = blockIdx.y, b = blockIdx.z;

    float s = 0.f;
    for (int dy = 0; dy < 3; ++dy) {
        int gy = y + dy - 1;
        if ((unsigned)gy >= HH) continue;     // uniform across block
        #pragma unroll
        for (int dx = 0; dx < 3; ++dx) {
            int gx = xx + dx - 1;
            if ((unsigned)gx >= WW) continue; // divergent only at tile edge
            const float4* cp = (const float4*)&cur[(((size_t)b * HH + gy) * WW + gx) * FF + j * 8];
            const float4* wp = (const float4*)&w_out[(dy * 3 + dx) * FF + j * 8];
            float4 c0 = cp[0], c1 = cp[1];
            float4 w0 = wp[0], w1 = wp[1];
            s += c0.x * w0.x + c0.y * w0.y + c0.z * w0.z + c0.w * w0.w
               + c1.x * w1.x + c1.y * w1.y + c1.z * w1.z + c1.w * w1.w;
        }
    }
    s += __shfl_xor(s, 1);
    s += __shfl_xor(s, 2);
    s += __shfl_xor(s, 4);
    if (j == 0)
        out[(((size_t)b * PRED_LEN + ti) * HH + y) * WW + xx] = sigf(s + b_out[0]);
}

// cur = relu(pred * w_proj + b_proj): (B,H,W,1) -> (B,H,W,64)
// thread per (pixel, 4-feature quad): 16 threads/pixel
__global__ __launch_bounds__(256) void dec_proj(
    const float* __restrict__ out, const float* __restrict__ w_proj,
    const float* __restrict__ b_proj, float* __restrict__ cur, int ti)
{
    size_t gt = (size_t)blockIdx.x * 256 + threadIdx.x;  // pix*16 + fq
    size_t pix = gt >> 4;
    int fq = (int)(gt & 15);
    int b  = (int)(pix >> 14);            // H*W = 16384
    int yx = (int)(pix & 16383);
    float pv = out[((size_t)b * PRED_LEN + ti) * (HH * WW) + yx];
    const float4 w  = ((const float4*)w_proj)[fq];
    const float4 bb = ((const float4*)b_proj)[fq];
    float4 o;
    o.x = fmaxf(fmaf(pv, w.x, bb.x), 0.f);
    o.y = fmaxf(fmaf(pv, w.y, bb.y), 0.f);
    o.z = fmaxf(fmaf(pv, w.z, bb.z), 0.f);
    o.w = fmaxf(fmaf(pv, w.w, bb.w), 0.f);
    ((float4*)cur)[gt] = o;
}

extern "C" void kernel_launch(void* const* d_in, const int* in_sizes, int n_in,
                              void* d_out, int out_size, void* d_ws, size_t ws_size,
                              hipStream_t stream)
{
    const float* x      = (const float*)d_in[0];
    const float* wk     = (const float*)d_in[1];
    const float* wr     = (const float*)d_in[2];
    const float* bias   = (const float*)d_in[3];
    const float* w_out  = (const float*)d_in[4];
    const float* b_out  = (const float*)d_in[5];
    const float* w_proj = (const float*)d_in[6];
    const float* b_proj = (const float*)d_in[7];
    float* out = (float*)d_out;

    const size_t SB = (size_t)BB * HH * WW * FF;   // 8388608 elems
    float* h_a = (float*)d_ws;
    float* h_b = h_a + SB;
    float* cb  = h_b + SB;

    hipMemsetAsync(h_a, 0, SB * sizeof(float), stream);
    hipMemsetAsync(cb,  0, SB * sizeof(float), stream);

    dim3 gs(WW / TW, HH, BB);
    float* bufs[2] = {h_a, h_b};
    for (int t = 0; t < TT; ++t) {
        lstm_step<<<gs, 256, 0, stream>>>(x, t, bufs[t & 1], cb, bufs[(t + 1) & 1],
                                          wk, wr, bias);
    }

    float* cur = bufs[0];  // final h after 12 steps
    for (int ti = 0; ti < PRED_LEN; ++ti) {
        dec_conv<<<dim3(WW / 32, HH, BB), 256, 0, stream>>>(cur, w_out, b_out, out, ti);
        dec_proj<<<(int)((SB / 4) / 256), 256, 0, stream>>>(out, w_proj, b_proj, cur, ti);
    }
}

// Round 2
// 1114.116 us; speedup vs baseline: 6.5609x; 6.5609x over previous
//
#include <hip/hip_runtime.h>
#include <math.h>

#define BB 8
#define TT 12
#define HH 128
#define WW 128
#define FF 64
#define GG 256   // 4*FF
#define PRED_LEN 6
#define TW 64    // pixels per block along W

typedef __attribute__((ext_vector_type(8))) short short8;
typedef __attribute__((ext_vector_type(4))) float floatx4;

__device__ __forceinline__ float sigf(float x) { return 1.f / (1.f + __expf(-x)); }
__device__ __forceinline__ float tanhfast(float x) { return 1.f - 2.f / (__expf(2.f * x) + 1.f); }

__device__ __forceinline__ unsigned short f2bf(float x) {
    unsigned u = __float_as_uint(x);
    u = (u + 0x7FFFu + ((u >> 16) & 1u)) >> 16;
    return (unsigned short)u;
}
__device__ __forceinline__ float bf2f(unsigned short u) {
    return __uint_as_float((unsigned)u << 16);
}

// Pack wr (3,3,64,256) fp32 -> bf16 B-fragments for mfma_f32_16x16x32_bf16.
// Entry e = ((tap*2+kc)*16 + nt)*64 + lane; lane = col + 16*kpart holds
// B[k][n], k = kc*32 + kpart*8 + j (j=0..7), n = nt*16 + col.
__global__ __launch_bounds__(256) void pack_wr(const float* __restrict__ wr,
                                               short8* __restrict__ packed)
{
    int e = blockIdx.x * 256 + threadIdx.x;   // 18432 entries
    int lane = e & 63;
    int rest = e >> 6;
    int nt  = rest & 15;
    int kcp = rest >> 4;       // tap*2+kc, 0..17
    int kc  = kcp & 1, tap = kcp >> 1;
    int col = lane & 15, kpart = lane >> 4;
    short8 v;
    #pragma unroll
    for (int j = 0; j < 8; ++j) {
        int k = kc * 32 + kpart * 8 + j;
        int gate = nt * 16 + col;
        v[j] = (short)f2bf(wr[((size_t)(tap * 64 + k)) * GG + gate]);
    }
    packed[e] = v;
}

// Fused ConvLSTM step with MFMA recurrent conv.
// Block = 64 px (one row segment) x 256 gates; 4 waves; wave w owns all 64 px
// x N-tiles {w, w+4, w+8, w+12} (so i,f,g,o per feature are thread-local).
__global__ __launch_bounds__(256) void lstm_step_mfma(
    const float* __restrict__ x,            // (B,T,H,W,1) fp32
    int t,
    const unsigned short* __restrict__ h_in,// (B,H,W,F) bf16
    float* __restrict__ c_buf,              // (B,H,W,F) fp32 in/out
    unsigned short* __restrict__ h_out,     // (B,H,W,F) bf16
    const short8* __restrict__ packedB,     // packed wr
    const float* __restrict__ wk,           // (3,3,1,4F) fp32
    const float* __restrict__ bias)         // (4F) fp32
{
    __shared__ __align__(16) unsigned short sh[3 * 66 * FF];  // swizzled bf16 h tile
    __shared__ float sx[3][66];

    const int tid = threadIdx.x;
    const int x0 = blockIdx.x * TW;
    const int y  = blockIdx.y;
    const int b  = blockIdx.z;
    char* shb = (char*)sh;

    // ---- stage h tile: 3 rows x 66 cols x 64 ch bf16, 16B chunks, XOR-swizzled ----
    for (int i = tid; i < 3 * 66 * 8; i += 256) {
        int cq  = i & 7;
        int rc  = i >> 3;
        int col = rc % 66, r = rc / 66;
        int gy = y + r - 1, gx = x0 + col - 1;
        uint4 v = make_uint4(0u, 0u, 0u, 0u);
        if ((unsigned)gy < HH && (unsigned)gx < WW)
            v = *(const uint4*)(h_in + ((((size_t)b * HH + gy) * WW + gx) * FF + cq * 8));
        int byte = ((r * 66 + col) * FF + cq * 8) * 2;
        byte ^= ((col & 7) << 4);
        *(uint4*)(shb + byte) = v;
    }
    // ---- stage x tile ----
    for (int i = tid; i < 3 * 66; i += 256) {
        int col = i % 66, r = i / 66;
        int gy = y + r - 1, gx = x0 + col - 1;
        float v = 0.f;
        if ((unsigned)gy < HH && (unsigned)gx < WW)
            v = x[(((size_t)b * TT + t) * HH + gy) * WW + gx];
        sx[r][col] = v;
    }
    __syncthreads();

    const int l  = tid & 63;
    const int w  = tid >> 6;     // wave id
    const int lc = l & 15;       // A row / C col within 16-tile
    const int kp = l >> 4;       // k-part

    floatx4 acc[4][4];
    #pragma unroll
    for (int m = 0; m < 4; ++m)
        #pragma unroll
        for (int q = 0; q < 4; ++q)
            acc[m][q] = (floatx4){0.f, 0.f, 0.f, 0.f};

    // ---- recurrent conv: 9 taps x 2 K-chunks, 16 MFMA each ----
    #pragma unroll
    for (int tap = 0; tap < 9; ++tap) {
        const int dy = tap / 3, dx = tap % 3;
        #pragma unroll
        for (int kc = 0; kc < 2; ++kc) {
            short8 af[4], bf[4];
            #pragma unroll
            for (int m = 0; m < 4; ++m) {
                int col = m * 16 + lc + dx;
                int byte = ((dy * 66 + col) * FF + kc * 32 + kp * 8) * 2;
                byte ^= ((col & 7) << 4);
                af[m] = *(const short8*)(shb + byte);
            }
            #pragma unroll
            for (int q = 0; q < 4; ++q)
                bf[q] = packedB[(size_t)((tap * 2 + kc) * 16 + (q * 4 + w)) * 64 + l];
            #pragma unroll
            for (int m = 0; m < 4; ++m)
                #pragma unroll
                for (int q = 0; q < 4; ++q)
                    acc[m][q] = __builtin_amdgcn_mfma_f32_16x16x32_bf16(
                        af[m], bf[q], acc[m][q], 0, 0, 0);
        }
    }

    // ---- epilogue: input conv (Cin=1) + bias + gates + cell update ----
    const int gcol = w * 16 + lc;   // feature index 0..63
    float bq[4], wkq[9][4];
    #pragma unroll
    for (int q = 0; q < 4; ++q) bq[q] = bias[q * 64 + gcol];
    #pragma unroll
    for (int tap = 0; tap < 9; ++tap)
        #pragma unroll
        for (int q = 0; q < 4; ++q)
            wkq[tap][q] = wk[tap * GG + q * 64 + gcol];

    #pragma unroll
    for (int m = 0; m < 4; ++m) {
        #pragma unroll
        for (int r = 0; r < 4; ++r) {
            int p = m * 16 + kp * 4 + r;   // C row = pixel within tile
            float s0 = acc[m][0][r] + bq[0];
            float s1 = acc[m][1][r] + bq[1];
            float s2 = acc[m][2][r] + bq[2];
            float s3 = acc[m][3][r] + bq[3];
            #pragma unroll
            for (int tap = 0; tap < 9; ++tap) {
                float xv = sx[tap / 3][p + (tap % 3)];
                s0 = fmaf(xv, wkq[tap][0], s0);
                s1 = fmaf(xv, wkq[tap][1], s1);
                s2 = fmaf(xv, wkq[tap][2], s2);
                s3 = fmaf(xv, wkq[tap][3], s3);
            }
            size_t idx = (((size_t)b * HH + y) * WW + (x0 + p)) * FF + gcol;
            float cp = c_buf[idx];
            float iv = sigf(s0);
            float fv = sigf(s1);
            float gv = tanhfast(s2);
            float ov = sigf(s3);
            float cn = fv * cp + iv * gv;
            float hn = ov * tanhfast(cn);
            c_buf[idx] = cn;
            h_out[idx] = f2bf(hn);
        }
    }
}

// pred = sigmoid(conv3x3(cur_bf16, w_out) + b_out): (B,H,W,64) -> (B,H,W,1)
__global__ __launch_bounds__(256) void dec_conv(
    const unsigned short* __restrict__ cur, const float* __restrict__ w_out,
    const float* __restrict__ b_out, float* __restrict__ out, int ti)
{
    int tid = threadIdx.x;
    int j  = tid & 7;
    int pp = tid >> 3;
    int xx = blockIdx.x * 32 + pp;
    int y = blockIdx.y, b = blockIdx.z;

    float s = 0.f;
    for (int dy = 0; dy < 3; ++dy) {
        int gy = y + dy - 1;
        if ((unsigned)gy >= HH) continue;
        #pragma unroll
        for (int dx = 0; dx < 3; ++dx) {
            int gx = xx + dx - 1;
            if ((unsigned)gx >= WW) continue;
            const uint4 cv = *(const uint4*)(cur + ((((size_t)b * HH + gy) * WW + gx) * FF + j * 8));
            const float4* wp = (const float4*)&w_out[(dy * 3 + dx) * FF + j * 8];
            float4 w0 = wp[0], w1 = wp[1];
            unsigned cx = cv.x, cy = cv.y, cz = cv.z, cw = cv.w;
            s += __uint_as_float(cx << 16) * w0.x + __uint_as_float(cx & 0xFFFF0000u) * w0.y
               + __uint_as_float(cy << 16) * w0.z + __uint_as_float(cy & 0xFFFF0000u) * w0.w
               + __uint_as_float(cz << 16) * w1.x + __uint_as_float(cz & 0xFFFF0000u) * w1.y
               + __uint_as_float(cw << 16) * w1.z + __uint_as_float(cw & 0xFFFF0000u) * w1.w;
        }
    }
    s += __shfl_xor(s, 1);
    s += __shfl_xor(s, 2);
    s += __shfl_xor(s, 4);
    if (j == 0)
        out[(((size_t)b * PRED_LEN + ti) * HH + y) * WW + xx] = sigf(s + b_out[0]);
}

// cur = relu(pred * w_proj + b_proj) stored bf16: (B,H,W,1) -> (B,H,W,64)
__global__ __launch_bounds__(256) void dec_proj(
    const float* __restrict__ out, const float* __restrict__ w_proj,
    const float* __restrict__ b_proj, unsigned short* __restrict__ cur, int ti)
{
    size_t gt = (size_t)blockIdx.x * 256 + threadIdx.x;  // pix*8 + fg
    size_t pix = gt >> 3;
    int fg = (int)(gt & 7);
    int b  = (int)(pix >> 14);            // H*W = 16384
    int yx = (int)(pix & 16383);
    float pv = out[((size_t)b * PRED_LEN + ti) * (HH * WW) + yx];
    const float4* wp = (const float4*)w_proj;
    const float4* bp = (const float4*)b_proj;
    float4 w0 = wp[fg * 2], w1 = wp[fg * 2 + 1];
    float4 b0 = bp[fg * 2], b1 = bp[fg * 2 + 1];
    short8 o;
    o[0] = (short)f2bf(fmaxf(fmaf(pv, w0.x, b0.x), 0.f));
    o[1] = (short)f2bf(fmaxf(fmaf(pv, w0.y, b0.y), 0.f));
    o[2] = (short)f2bf(fmaxf(fmaf(pv, w0.z, b0.z), 0.f));
    o[3] = (short)f2bf(fmaxf(fmaf(pv, w0.w, b0.w), 0.f));
    o[4] = (short)f2bf(fmaxf(fmaf(pv, w1.x, b1.x), 0.f));
    o[5] = (short)f2bf(fmaxf(fmaf(pv, w1.y, b1.y), 0.f));
    o[6] = (short)f2bf(fmaxf(fmaf(pv, w1.z, b1.z), 0.f));
    o[7] = (short)f2bf(fmaxf(fmaf(pv, w1.w, b1.w), 0.f));
    *(short8*)(cur + pix * FF + fg * 8) = o;
}

extern "C" void kernel_launch(void* const* d_in, const int* in_sizes, int n_in,
                              void* d_out, int out_size, void* d_ws, size_t ws_size,
                              hipStream_t stream)
{
    const float* x      = (const float*)d_in[0];
    const float* wk     = (const float*)d_in[1];
    const float* wr     = (const float*)d_in[2];
    const float* bias   = (const float*)d_in[3];
    const float* w_out  = (const float*)d_in[4];
    const float* b_out  = (const float*)d_in[5];
    const float* w_proj = (const float*)d_in[6];
    const float* b_proj = (const float*)d_in[7];
    float* out = (float*)d_out;

    const size_t SB = (size_t)BB * HH * WW * FF;   // 8388608 elems
    unsigned short* h_a = (unsigned short*)d_ws;                 // bf16, 16.8 MB
    unsigned short* h_b = h_a + SB;                              // bf16, 16.8 MB
    float* cb = (float*)((char*)d_ws + 2 * SB * sizeof(unsigned short)); // fp32, 33.5 MB
    short8* packed = (short8*)((char*)cb + SB * sizeof(float));  // 294912 B

    hipMemsetAsync(h_a, 0, SB * sizeof(unsigned short), stream);
    hipMemsetAsync(cb, 0, SB * sizeof(float), stream);
    pack_wr<<<72, 256, 0, stream>>>(wr, packed);

    dim3 gs(WW / TW, HH, BB);
    unsigned short* bufs[2] = {h_a, h_b};
    for (int t = 0; t < TT; ++t) {
        lstm_step_mfma<<<gs, 256, 0, stream>>>(x, t, bufs[t & 1], cb, bufs[(t + 1) & 1],
                                               packed, wk, bias);
    }

    unsigned short* cur = bufs[0];  // final h (t=11 writes bufs[0])
    for (int ti = 0; ti < PRED_LEN; ++ti) {
        dec_conv<<<dim3(WW / 32, HH, BB), 256, 0, stream>>>(cur, w_out, b_out, out, ti);
        dec_proj<<<(int)((SB / 8) / 256), 256, 0, stream>>>(out, w_proj, b_proj, cur, ti);
    }
}

// Round 4
// 1037.654 us; speedup vs baseline: 7.0444x; 1.0737x over previous
//
#include <hip/hip_runtime.h>
#include <math.h>

#define BB 8
#define TT 12
#define HH 128
#define WW 128
#define FF 64
#define GG 256   // 4*FF
#define PRED_LEN 6
#define TW 64    // pixels per block along W

typedef __attribute__((ext_vector_type(8))) short short8;
typedef __attribute__((ext_vector_type(4))) float floatx4;

__device__ __forceinline__ float sigf(float x) { return 1.f / (1.f + __expf(-x)); }
__device__ __forceinline__ float tanhfast(float x) { return 1.f - 2.f / (__expf(2.f * x) + 1.f); }

__device__ __forceinline__ unsigned short f2bf(float x) {
    unsigned u = __float_as_uint(x);
    u = (u + 0x7FFFu + ((u >> 16) & 1u)) >> 16;
    return (unsigned short)u;
}

// Pack wr (3,3,64,256) fp32 -> bf16 B-fragments for mfma_f32_16x16x32_bf16.
// Chunk c = tap*2+kc; entry e = (c*16 + nt)*64 + lane; lane = col + 16*kpart
// holds B[k][n], k = kc*32 + kpart*8 + j, n = nt*16 + col.  (R1-proven.)
__global__ __launch_bounds__(256) void pack_wr(const float* __restrict__ wr,
                                               short8* __restrict__ packed)
{
    int e = blockIdx.x * 256 + threadIdx.x;   // 18432 entries
    int lane = e & 63;
    int rest = e >> 6;
    int nt  = rest & 15;
    int kcp = rest >> 4;       // tap*2+kc, 0..17
    int kc  = kcp & 1, tap = kcp >> 1;
    int col = lane & 15, kpart = lane >> 4;
    short8 v;
    #pragma unroll
    for (int j = 0; j < 8; ++j) {
        int k = kc * 32 + kpart * 8 + j;
        int gate = nt * 16 + col;
        v[j] = (short)f2bf(wr[((size_t)(tap * 64 + k)) * GG + gate]);
    }
    packed[e] = v;
}

// Fused ConvLSTM step: recurrent conv on MFMA (depth-2 register pipeline),
// input conv + bias + gates in fp32 epilogue (R1-proven math).
// Block = 64 px x 256 gates; 4 waves; wave w owns N-tiles {w, w+4, w+8, w+12}
// so i,f,g,o per feature are thread-local in the C fragments.
template<bool FIRST>
__global__ __launch_bounds__(256) void lstm_step_mfma(
    const float* __restrict__ x,             // (B,T,H,W,1) fp32
    int t,
    const unsigned short* __restrict__ h_in, // (B,H,W,F) bf16
    float* __restrict__ c_buf,               // (B,H,W,F) fp32 in/out
    unsigned short* __restrict__ h_out,      // (B,H,W,F) bf16
    const short8* __restrict__ packedB,      // packed wr
    const float* __restrict__ wk,            // (3,3,1,4F) fp32
    const float* __restrict__ bias)          // (4F) fp32
{
    __shared__ __align__(16) unsigned short sh[3 * 66 * FF];  // swizzled bf16 h tile
    __shared__ float sx[3][66];

    const int tid = threadIdx.x;
    const int x0 = blockIdx.x * TW;
    const int y  = blockIdx.y;
    const int b  = blockIdx.z;
    char* shb = (char*)sh;

    if (!FIRST) {
        // stage h tile: 3 rows x 66 cols x 64 ch bf16, 16B chunks, XOR-swizzled
        for (int i = tid; i < 3 * 66 * 8; i += 256) {
            int cq  = i & 7;
            int rc  = i >> 3;
            int col = rc % 66, r = rc / 66;
            int gy = y + r - 1, gx = x0 + col - 1;
            uint4 v = make_uint4(0u, 0u, 0u, 0u);
            if ((unsigned)gy < HH && (unsigned)gx < WW)
                v = *(const uint4*)(h_in + ((((size_t)b * HH + gy) * WW + gx) * FF + cq * 8));
            int byte = ((r * 66 + col) * FF + cq * 8) * 2;
            byte ^= ((col & 7) << 4);
            *(uint4*)(shb + byte) = v;
        }
    }
    // stage x tile (fp32)
    for (int i = tid; i < 3 * 66; i += 256) {
        int col = i % 66, r = i / 66;
        int gy = y + r - 1, gx = x0 + col - 1;
        float v = 0.f;
        if ((unsigned)gy < HH && (unsigned)gx < WW)
            v = x[(((size_t)b * TT + t) * HH + gy) * WW + gx];
        sx[r][col] = v;
    }
    __syncthreads();

    const int l  = tid & 63;
    const int w  = tid >> 6;
    const int lc = l & 15;
    const int kp = l >> 4;
    const int gcol = w * 16 + lc;   // feature index 0..63

    // hoist wk/bias loads so they overlap the MFMA section (L2-hot, coalesced)
    float bq[4], wkq[9][4];
    #pragma unroll
    for (int q = 0; q < 4; ++q) bq[q] = bias[q * 64 + gcol];
    #pragma unroll
    for (int tap = 0; tap < 9; ++tap)
        #pragma unroll
        for (int q = 0; q < 4; ++q)
            wkq[tap][q] = wk[tap * GG + q * 64 + gcol];

    floatx4 acc[4][4];
    #pragma unroll
    for (int m = 0; m < 4; ++m)
        #pragma unroll
        for (int q = 0; q < 4; ++q)
            acc[m][q] = (floatx4){0.f, 0.f, 0.f, 0.f};

#define LD_AF(AF, cc) do { \
    const int tap_ = (cc) >> 1, kc_ = (cc) & 1, dy_ = tap_ / 3, dx_ = tap_ % 3; \
    _Pragma("unroll") for (int m_ = 0; m_ < 4; ++m_) { \
        const int col_ = m_ * 16 + lc + dx_; \
        int byte_ = ((dy_ * 66 + col_) * FF + kc_ * 32 + kp * 8) * 2; \
        byte_ ^= ((col_ & 7) << 4); \
        AF[m_] = *(const short8*)(shb + byte_); } \
    } while (0)

#define LD_BF(BF, cc) do { \
    _Pragma("unroll") for (int q_ = 0; q_ < 4; ++q_) \
        BF[q_] = packedB[(size_t)((cc) * 16 + (q_ * 4 + w)) * 64 + l]; } while (0)

#define DO_MFMA(AF, BF) do { \
    _Pragma("unroll") for (int m_ = 0; m_ < 4; ++m_) \
        _Pragma("unroll") for (int q_ = 0; q_ < 4; ++q_) \
            acc[m_][q_] = __builtin_amdgcn_mfma_f32_16x16x32_bf16(AF[m_], BF[q_], acc[m_][q_], 0, 0, 0); \
    } while (0)

    if (!FIRST) {
        short8 afA[4], bfA[4], afB[4], bfB[4];
        LD_AF(afA, 0); LD_BF(bfA, 0);
        #pragma unroll
        for (int c = 0; c < 18; c += 2) {
            LD_AF(afB, c + 1); LD_BF(bfB, c + 1);
            DO_MFMA(afA, bfA);
            if (c + 2 < 18) { LD_AF(afA, c + 2); LD_BF(bfA, c + 2); }
            DO_MFMA(afB, bfB);
        }
    }
#undef LD_AF
#undef LD_BF
#undef DO_MFMA

    // epilogue: bias + input conv (fp32) + gates + cell update (Keras i,f,g,o)
    #pragma unroll
    for (int m = 0; m < 4; ++m) {
        #pragma unroll
        for (int r = 0; r < 4; ++r) {
            int p = m * 16 + kp * 4 + r;   // pixel within tile
            float s0 = acc[m][0][r] + bq[0];
            float s1 = acc[m][1][r] + bq[1];
            float s2 = acc[m][2][r] + bq[2];
            float s3 = acc[m][3][r] + bq[3];
            #pragma unroll
            for (int tap = 0; tap < 9; ++tap) {
                float xv = sx[tap / 3][p + (tap % 3)];
                s0 = fmaf(xv, wkq[tap][0], s0);
                s1 = fmaf(xv, wkq[tap][1], s1);
                s2 = fmaf(xv, wkq[tap][2], s2);
                s3 = fmaf(xv, wkq[tap][3], s3);
            }
            size_t idx = (((size_t)b * HH + y) * WW + (x0 + p)) * FF + gcol;
            float cp = FIRST ? 0.f : c_buf[idx];
            float iv = sigf(s0);
            float fv = sigf(s1);
            float gv = tanhfast(s2);
            float ov = sigf(s3);
            float cn = fv * cp + iv * gv;
            float hn = ov * tanhfast(cn);
            c_buf[idx] = cn;
            h_out[idx] = f2bf(hn);
        }
    }
}

// Fused decoder iteration:
//   pred = sigmoid(conv3x3(cur_in, w_out) + b_out)  -> out[:, ti]
//   cur_out = relu(pred * w_proj + b_proj)          (bf16)
__global__ __launch_bounds__(256) void dec_fused(
    const unsigned short* __restrict__ cur_in, const float* __restrict__ w_out,
    const float* __restrict__ b_out, const float* __restrict__ w_proj,
    const float* __restrict__ b_proj, float* __restrict__ out,
    unsigned short* __restrict__ cur_out, int ti)
{
    int tid = threadIdx.x;
    int j  = tid & 7;
    int pp = tid >> 3;
    int xx = blockIdx.x * 32 + pp;
    int y = blockIdx.y, b = blockIdx.z;

    float s = 0.f;
    for (int dy = 0; dy < 3; ++dy) {
        int gy = y + dy - 1;
        if ((unsigned)gy >= HH) continue;
        #pragma unroll
        for (int dx = 0; dx < 3; ++dx) {
            int gx = xx + dx - 1;
            if ((unsigned)gx >= WW) continue;
            const uint4 cv = *(const uint4*)(cur_in + ((((size_t)b * HH + gy) * WW + gx) * FF + j * 8));
            const float4* wp = (const float4*)&w_out[(dy * 3 + dx) * FF + j * 8];
            float4 w0 = wp[0], w1 = wp[1];
            unsigned cx = cv.x, cy = cv.y, cz = cv.z, cw = cv.w;
            s += __uint_as_float(cx << 16) * w0.x + __uint_as_float(cx & 0xFFFF0000u) * w0.y
               + __uint_as_float(cy << 16) * w0.z + __uint_as_float(cy & 0xFFFF0000u) * w0.w
               + __uint_as_float(cz << 16) * w1.x + __uint_as_float(cz & 0xFFFF0000u) * w1.y
               + __uint_as_float(cw << 16) * w1.z + __uint_as_float(cw & 0xFFFF0000u) * w1.w;
        }
    }
    s += __shfl_xor(s, 1);
    s += __shfl_xor(s, 2);
    s += __shfl_xor(s, 4);
    float pv = sigf(s + b_out[0]);

    size_t pix = (((size_t)b * HH + y) * WW + xx);
    if (j == 0)
        out[((size_t)b * PRED_LEN + ti) * (HH * WW) + (size_t)y * WW + xx] = pv;

    const float4* wp = (const float4*)w_proj;
    const float4* bp = (const float4*)b_proj;
    float4 w0 = wp[j * 2], w1 = wp[j * 2 + 1];
    float4 b0 = bp[j * 2], b1 = bp[j * 2 + 1];
    short8 o;
    o[0] = (short)f2bf(fmaxf(fmaf(pv, w0.x, b0.x), 0.f));
    o[1] = (short)f2bf(fmaxf(fmaf(pv, w0.y, b0.y), 0.f));
    o[2] = (short)f2bf(fmaxf(fmaf(pv, w0.z, b0.z), 0.f));
    o[3] = (short)f2bf(fmaxf(fmaf(pv, w0.w, b0.w), 0.f));
    o[4] = (short)f2bf(fmaxf(fmaf(pv, w1.x, b1.x), 0.f));
    o[5] = (short)f2bf(fmaxf(fmaf(pv, w1.y, b1.y), 0.f));
    o[6] = (short)f2bf(fmaxf(fmaf(pv, w1.z, b1.z), 0.f));
    o[7] = (short)f2bf(fmaxf(fmaf(pv, w1.w, b1.w), 0.f));
    *(short8*)(cur_out + pix * FF + j * 8) = o;
}

extern "C" void kernel_launch(void* const* d_in, const int* in_sizes, int n_in,
                              void* d_out, int out_size, void* d_ws, size_t ws_size,
                              hipStream_t stream)
{
    const float* x      = (const float*)d_in[0];
    const float* wk     = (const float*)d_in[1];
    const float* wr     = (const float*)d_in[2];
    const float* bias   = (const float*)d_in[3];
    const float* w_out  = (const float*)d_in[4];
    const float* b_out  = (const float*)d_in[5];
    const float* w_proj = (const float*)d_in[6];
    const float* b_proj = (const float*)d_in[7];
    float* out = (float*)d_out;

    const size_t SB = (size_t)BB * HH * WW * FF;   // 8388608 elems
    unsigned short* h_a = (unsigned short*)d_ws;
    unsigned short* h_b = h_a + SB;
    float* cb = (float*)((char*)d_ws + 2 * SB * sizeof(unsigned short));
    short8* packed = (short8*)((char*)cb + SB * sizeof(float));  // 18432*16 B

    hipMemsetAsync(h_a, 0, SB * sizeof(unsigned short), stream);
    hipMemsetAsync(cb, 0, SB * sizeof(float), stream);
    pack_wr<<<72, 256, 0, stream>>>(wr, packed);

    dim3 gs(WW / TW, HH, BB);
    unsigned short* bufs[2] = {h_a, h_b};
    lstm_step_mfma<true><<<gs, 256, 0, stream>>>(x, 0, bufs[0], cb, bufs[1], packed, wk, bias);
    for (int t = 1; t < TT; ++t) {
        lstm_step_mfma<false><<<gs, 256, 0, stream>>>(x, t, bufs[t & 1], cb,
                                                      bufs[(t + 1) & 1], packed, wk, bias);
    }

    for (int ti = 0; ti < PRED_LEN; ++ti) {
        dec_fused<<<dim3(WW / 32, HH, BB), 256, 0, stream>>>(
            bufs[ti & 1], w_out, b_out, w_proj, b_proj, out, bufs[(ti + 1) & 1], ti);
    }
}

// Round 5
// 892.363 us; speedup vs baseline: 8.1913x; 1.1628x over previous
//
#include <hip/hip_runtime.h>
#include <math.h>

#define BB 8
#define TT 12
#define HH 128
#define WW 128
#define FF 64
#define GG 256   // 4*FF
#define PRED_LEN 6
#define TW 64    // pixels per block along W

typedef __attribute__((ext_vector_type(8))) short short8;
typedef __attribute__((ext_vector_type(4))) float floatx4;

__device__ __forceinline__ float sigf(float x) { return 1.f / (1.f + __expf(-x)); }
__device__ __forceinline__ float tanhfast(float x) { return 1.f - 2.f / (__expf(2.f * x) + 1.f); }

__device__ __forceinline__ unsigned short f2bf(float x) {
    unsigned u = __float_as_uint(x);
    u = (u + 0x7FFFu + ((u >> 16) & 1u)) >> 16;
    return (unsigned short)u;
}

// Pack wr (3,3,64,256) fp32 -> bf16 B-fragments for mfma_f32_16x16x32_bf16.
// Chunk c = tap*2+kc; entry e = (c*16 + nt)*64 + lane; lane = col + 16*kpart
// holds B[k][n], k = kc*32 + kpart*8 + j, n = nt*16 + col.  (R1-proven.)
__global__ __launch_bounds__(256) void pack_wr(const float* __restrict__ wr,
                                               short8* __restrict__ packed)
{
    int e = blockIdx.x * 256 + threadIdx.x;   // 18432 entries
    int lane = e & 63;
    int rest = e >> 6;
    int nt  = rest & 15;
    int kcp = rest >> 4;       // tap*2+kc, 0..17
    int kc  = kcp & 1, tap = kcp >> 1;
    int col = lane & 15, kpart = lane >> 4;
    short8 v;
    #pragma unroll
    for (int j = 0; j < 8; ++j) {
        int k = kc * 32 + kpart * 8 + j;
        int gate = nt * 16 + col;
        v[j] = (short)f2bf(wr[((size_t)(tap * 64 + k)) * GG + gate]);
    }
    packed[e] = v;
}

// Fused ConvLSTM step: recurrent conv on MFMA, input conv + gates in fp32
// epilogue. Block = 64 px x 256 gates; 4 waves; wave w owns N-tiles
// {w, w+4, w+8, w+12} so i,f,g,o per feature are thread-local.
// __launch_bounds__(256,4): 4 blocks/CU -> allocator targets <=128 unified
// VGPR+AGPR (R3 was 96+64=160 -> 2-waves/SIMD occupancy cliff).
template<bool FIRST>
__global__ __launch_bounds__(256, 4) void lstm_step_mfma(
    const float* __restrict__ x,             // (B,T,H,W,1) fp32
    int t,
    const unsigned short* __restrict__ h_in, // (B,H,W,F) bf16
    float* __restrict__ c_buf,               // (B,H,W,F) fp32 in/out
    unsigned short* __restrict__ h_out,      // (B,H,W,F) bf16
    const short8* __restrict__ packedB,      // packed wr
    const float* __restrict__ wk,            // (3,3,1,4F) fp32
    const float* __restrict__ bias)          // (4F) fp32
{
    __shared__ __align__(16) unsigned short sh[3 * 66 * FF];  // swizzled bf16 h tile
    __shared__ float sx[3][66];

    const int tid = threadIdx.x;
    const int x0 = blockIdx.x * TW;
    const int y  = blockIdx.y;
    const int b  = blockIdx.z;
    char* shb = (char*)sh;

    if (!FIRST) {
        // stage h tile: 3 rows x 66 cols x 64 ch bf16, 16B chunks, XOR-swizzled
        for (int i = tid; i < 3 * 66 * 8; i += 256) {
            int cq  = i & 7;
            int rc  = i >> 3;
            int col = rc % 66, r = rc / 66;
            int gy = y + r - 1, gx = x0 + col - 1;
            uint4 v = make_uint4(0u, 0u, 0u, 0u);
            if ((unsigned)gy < HH && (unsigned)gx < WW)
                v = *(const uint4*)(h_in + ((((size_t)b * HH + gy) * WW + gx) * FF + cq * 8));
            int byte = ((r * 66 + col) * FF + cq * 8) * 2;
            byte ^= ((col & 7) << 4);
            *(uint4*)(shb + byte) = v;
        }
    }
    // stage x tile (fp32)
    for (int i = tid; i < 3 * 66; i += 256) {
        int col = i % 66, r = i / 66;
        int gy = y + r - 1, gx = x0 + col - 1;
        float v = 0.f;
        if ((unsigned)gy < HH && (unsigned)gx < WW)
            v = x[(((size_t)b * TT + t) * HH + gy) * WW + gx];
        sx[r][col] = v;
    }
    __syncthreads();

    const int l  = tid & 63;
    const int w  = tid >> 6;
    const int lc = l & 15;
    const int kp = l >> 4;
    const int gcol = w * 16 + lc;   // feature index 0..63

    floatx4 acc[4][4];
    #pragma unroll
    for (int m = 0; m < 4; ++m)
        #pragma unroll
        for (int q = 0; q < 4; ++q)
            acc[m][q] = (floatx4){0.f, 0.f, 0.f, 0.f};

    if (!FIRST) {
        // single-buffered MFMA loop; fully unrolled, scheduler hoists loads
        // within the 128-reg budget.
        #pragma unroll
        for (int c = 0; c < 18; ++c) {
            const int tap_ = c >> 1, kc_ = c & 1, dy_ = tap_ / 3, dx_ = tap_ % 3;
            short8 af[4], bf[4];
            #pragma unroll
            for (int m_ = 0; m_ < 4; ++m_) {
                const int col_ = m_ * 16 + lc + dx_;
                int byte_ = ((dy_ * 66 + col_) * FF + kc_ * 32 + kp * 8) * 2;
                byte_ ^= ((col_ & 7) << 4);
                af[m_] = *(const short8*)(shb + byte_);
            }
            #pragma unroll
            for (int q_ = 0; q_ < 4; ++q_)
                bf[q_] = packedB[(size_t)(c * 16 + (q_ * 4 + w)) * 64 + l];
            #pragma unroll
            for (int m_ = 0; m_ < 4; ++m_)
                #pragma unroll
                for (int q_ = 0; q_ < 4; ++q_)
                    acc[m_][q_] = __builtin_amdgcn_mfma_f32_16x16x32_bf16(
                        af[m_], bf[q_], acc[m_][q_], 0, 0, 0);
        }
    }

    // epilogue: wk/bias loaded HERE (not hoisted across the MFMA loop)
    float bq[4], wkq[9][4];
    #pragma unroll
    for (int q = 0; q < 4; ++q) bq[q] = bias[q * 64 + gcol];
    #pragma unroll
    for (int tap = 0; tap < 9; ++tap)
        #pragma unroll
        for (int q = 0; q < 4; ++q)
            wkq[tap][q] = wk[tap * GG + q * 64 + gcol];

    #pragma unroll
    for (int m = 0; m < 4; ++m) {
        #pragma unroll
        for (int r = 0; r < 4; ++r) {
            int p = m * 16 + kp * 4 + r;   // pixel within tile
            float s0 = acc[m][0][r] + bq[0];
            float s1 = acc[m][1][r] + bq[1];
            float s2 = acc[m][2][r] + bq[2];
            float s3 = acc[m][3][r] + bq[3];
            #pragma unroll
            for (int tap = 0; tap < 9; ++tap) {
                float xv = sx[tap / 3][p + (tap % 3)];
                s0 = fmaf(xv, wkq[tap][0], s0);
                s1 = fmaf(xv, wkq[tap][1], s1);
                s2 = fmaf(xv, wkq[tap][2], s2);
                s3 = fmaf(xv, wkq[tap][3], s3);
            }
            size_t idx = (((size_t)b * HH + y) * WW + (x0 + p)) * FF + gcol;
            float cp = FIRST ? 0.f : c_buf[idx];
            float iv = sigf(s0);
            float fv = sigf(s1);
            float gv = tanhfast(s2);
            float ov = sigf(s3);
            float cn = fv * cp + iv * gv;
            float hn = ov * tanhfast(cn);
            c_buf[idx] = cn;
            h_out[idx] = f2bf(hn);
        }
    }
}

// Fused decoder iteration:
//   pred = sigmoid(conv3x3(cur_in, w_out) + b_out)  -> out[:, ti]
//   cur_out = relu(pred * w_proj + b_proj)          (bf16)
__global__ __launch_bounds__(256) void dec_fused(
    const unsigned short* __restrict__ cur_in, const float* __restrict__ w_out,
    const float* __restrict__ b_out, const float* __restrict__ w_proj,
    const float* __restrict__ b_proj, float* __restrict__ out,
    unsigned short* __restrict__ cur_out, int ti)
{
    int tid = threadIdx.x;
    int j  = tid & 7;
    int pp = tid >> 3;
    int xx = blockIdx.x * 32 + pp;
    int y = blockIdx.y, b = blockIdx.z;

    float s = 0.f;
    for (int dy = 0; dy < 3; ++dy) {
        int gy = y + dy - 1;
        if ((unsigned)gy >= HH) continue;
        #pragma unroll
        for (int dx = 0; dx < 3; ++dx) {
            int gx = xx + dx - 1;
            if ((unsigned)gx >= WW) continue;
            const uint4 cv = *(const uint4*)(cur_in + ((((size_t)b * HH + gy) * WW + gx) * FF + j * 8));
            const float4* wp = (const float4*)&w_out[(dy * 3 + dx) * FF + j * 8];
            float4 w0 = wp[0], w1 = wp[1];
            unsigned cx = cv.x, cy = cv.y, cz = cv.z, cw = cv.w;
            s += __uint_as_float(cx << 16) * w0.x + __uint_as_float(cx & 0xFFFF0000u) * w0.y
               + __uint_as_float(cy << 16) * w0.z + __uint_as_float(cy & 0xFFFF0000u) * w0.w
               + __uint_as_float(cz << 16) * w1.x + __uint_as_float(cz & 0xFFFF0000u) * w1.y
               + __uint_as_float(cw << 16) * w1.z + __uint_as_float(cw & 0xFFFF0000u) * w1.w;
        }
    }
    s += __shfl_xor(s, 1);
    s += __shfl_xor(s, 2);
    s += __shfl_xor(s, 4);
    float pv = sigf(s + b_out[0]);

    size_t pix = (((size_t)b * HH + y) * WW + xx);
    if (j == 0)
        out[((size_t)b * PRED_LEN + ti) * (HH * WW) + (size_t)y * WW + xx] = pv;

    const float4* wp = (const float4*)w_proj;
    const float4* bp = (const float4*)b_proj;
    float4 w0 = wp[j * 2], w1 = wp[j * 2 + 1];
    float4 b0 = bp[j * 2], b1 = bp[j * 2 + 1];
    short8 o;
    o[0] = (short)f2bf(fmaxf(fmaf(pv, w0.x, b0.x), 0.f));
    o[1] = (short)f2bf(fmaxf(fmaf(pv, w0.y, b0.y), 0.f));
    o[2] = (short)f2bf(fmaxf(fmaf(pv, w0.z, b0.z), 0.f));
    o[3] = (short)f2bf(fmaxf(fmaf(pv, w0.w, b0.w), 0.f));
    o[4] = (short)f2bf(fmaxf(fmaf(pv, w1.x, b1.x), 0.f));
    o[5] = (short)f2bf(fmaxf(fmaf(pv, w1.y, b1.y), 0.f));
    o[6] = (short)f2bf(fmaxf(fmaf(pv, w1.z, b1.z), 0.f));
    o[7] = (short)f2bf(fmaxf(fmaf(pv, w1.w, b1.w), 0.f));
    *(short8*)(cur_out + pix * FF + j * 8) = o;
}

extern "C" void kernel_launch(void* const* d_in, const int* in_sizes, int n_in,
                              void* d_out, int out_size, void* d_ws, size_t ws_size,
                              hipStream_t stream)
{
    const float* x      = (const float*)d_in[0];
    const float* wk     = (const float*)d_in[1];
    const float* wr     = (const float*)d_in[2];
    const float* bias   = (const float*)d_in[3];
    const float* w_out  = (const float*)d_in[4];
    const float* b_out  = (const float*)d_in[5];
    const float* w_proj = (const float*)d_in[6];
    const float* b_proj = (const float*)d_in[7];
    float* out = (float*)d_out;

    const size_t SB = (size_t)BB * HH * WW * FF;   // 8388608 elems
    unsigned short* h_a = (unsigned short*)d_ws;
    unsigned short* h_b = h_a + SB;
    float* cb = (float*)((char*)d_ws + 2 * SB * sizeof(unsigned short));
    short8* packed = (short8*)((char*)cb + SB * sizeof(float));  // 18432*16 B

    pack_wr<<<72, 256, 0, stream>>>(wr, packed);

    dim3 gs(WW / TW, HH, BB);
    unsigned short* bufs[2] = {h_a, h_b};
    // FIRST writes every c/h element before any read -> no memset needed.
    lstm_step_mfma<true><<<gs, 256, 0, stream>>>(x, 0, bufs[0], cb, bufs[1], packed, wk, bias);
    for (int t = 1; t < TT; ++t) {
        lstm_step_mfma<false><<<gs, 256, 0, stream>>>(x, t, bufs[t & 1], cb,
                                                      bufs[(t + 1) & 1], packed, wk, bias);
    }

    for (int ti = 0; ti < PRED_LEN; ++ti) {
        dec_fused<<<dim3(WW / 32, HH, BB), 256, 0, stream>>>(
            bufs[ti & 1], w_out, b_out, w_proj, b_proj, out, bufs[(ti + 1) & 1], ti);
    }
}

// Round 6
// 831.190 us; speedup vs baseline: 8.7942x; 1.0736x over previous
//
#include <hip/hip_runtime.h>
#include <math.h>

#define BB 8
#define TT 12
#define HH 128
#define WW 128
#define FF 64
#define GG 256   // 4*FF
#define PRED_LEN 6
#define TW 64    // pixels per block along W

typedef __attribute__((ext_vector_type(8))) short short8;
typedef __attribute__((ext_vector_type(4))) float floatx4;

__device__ __forceinline__ float sigf(float x) { return 1.f / (1.f + __expf(-x)); }
__device__ __forceinline__ float tanhfast(float x) { return 1.f - 2.f / (__expf(2.f * x) + 1.f); }

__device__ __forceinline__ unsigned short f2bf(float x) {
    unsigned u = __float_as_uint(x);
    u = (u + 0x7FFFu + ((u >> 16) & 1u)) >> 16;
    return (unsigned short)u;
}

// Pack B-fragments for mfma_f32_16x16x32_bf16.
// Chunks 0..17 (wr): c = tap*2+kc; lane = col + 16*kpart holds B[k][n],
//   k = kc*32 + kpart*8 + j, n = nt*16 + col.  (R1-proven.)
// Chunk 18 (x-conv + bias): B[k][n] = k<9 ? wk[k][n] : k==9 ? bias[n] : 0.
//   (R2's bug: this slot was 1.0 instead of bias[n] -> +1.0 on every gate.)
__global__ __launch_bounds__(256) void pack_wr(
    const float* __restrict__ wr, const float* __restrict__ wk,
    const float* __restrict__ bias, short8* __restrict__ packed)
{
    int e = blockIdx.x * 256 + threadIdx.x;   // 19456 entries
    if (e >= 19 * 16 * 64) return;
    int lane = e & 63;
    int rest = e >> 6;
    int nt = rest & 15;
    int ch = rest >> 4;        // 0..18
    int col = lane & 15, kpart = lane >> 4;
    int n = nt * 16 + col;
    short8 v;
    if (ch < 18) {
        int kc = ch & 1, tap = ch >> 1;
        #pragma unroll
        for (int j = 0; j < 8; ++j) {
            int k = kc * 32 + kpart * 8 + j;
            v[j] = (short)f2bf(wr[((size_t)(tap * 64 + k)) * GG + n]);
        }
    } else {
        #pragma unroll
        for (int j = 0; j < 8; ++j) {
            int k = kpart * 8 + j;
            unsigned short r = 0;
            if (k < 9) r = f2bf(wk[k * GG + n]);
            else if (k == 9) r = f2bf(bias[n]);   // bias row (A has 1.0 there)
            v[j] = (short)r;
        }
    }
    packed[e] = v;
}

// Fused ConvLSTM step: recurrent conv + input conv + bias all on MFMA,
// gates/cell update in fp32 epilogue. Block = 64 px x 256 gates; 4 waves;
// wave w owns N-tiles {w, w+4, w+8, w+12} so i,f,g,o are thread-local.
// __launch_bounds__(256,4): keep unified VGPR+AGPR <=128 (R4-proven).
template<bool FIRST>
__global__ __launch_bounds__(256, 4) void lstm_step_mfma(
    const float* __restrict__ x,             // (B,T,H,W,1) fp32
    int t,
    const unsigned short* __restrict__ h_in, // (B,H,W,F) bf16
    float* __restrict__ c_buf,               // (B,H,W,F) fp32 in/out
    unsigned short* __restrict__ h_out,      // (B,H,W,F) bf16
    const short8* __restrict__ packedB)      // packed wr | wk+bias
{
    __shared__ __align__(16) unsigned short sh[3 * 66 * FF];  // swizzled bf16 h tile
    __shared__ __align__(16) unsigned short sxa[64 * 32];     // swizzled x A-fragments
    __shared__ float sx[3][66];

    const int tid = threadIdx.x;
    const int x0 = blockIdx.x * TW;
    const int y  = blockIdx.y;
    const int b  = blockIdx.z;
    char* shb = (char*)sh;

    if (!FIRST) {
        // stage h tile: 3 rows x 66 cols x 64 ch bf16, 16B chunks, XOR-swizzled
        for (int i = tid; i < 3 * 66 * 8; i += 256) {
            int cq  = i & 7;
            int rc  = i >> 3;
            int col = rc % 66, r = rc / 66;
            int gy = y + r - 1, gx = x0 + col - 1;
            uint4 v = make_uint4(0u, 0u, 0u, 0u);
            if ((unsigned)gy < HH && (unsigned)gx < WW)
                v = *(const uint4*)(h_in + ((((size_t)b * HH + gy) * WW + gx) * FF + cq * 8));
            int byte = ((r * 66 + col) * FF + cq * 8) * 2;
            byte ^= ((col & 7) << 4);
            *(uint4*)(shb + byte) = v;
        }
    }
    // stage x tile (fp32)
    for (int i = tid; i < 3 * 66; i += 256) {
        int col = i % 66, r = i / 66;
        int gy = y + r - 1, gx = x0 + col - 1;
        float v = 0.f;
        if ((unsigned)gy < HH && (unsigned)gx < WW)
            v = x[(((size_t)b * TT + t) * HH + gy) * WW + gx];
        sx[r][col] = v;
    }
    __syncthreads();

    // build x A-fragment tile: sxa[px][k] = k<9 ? tap k : k==9 ? 1.0 : 0
    {
        int px = tid >> 2, kpc = tid & 3;
        short8 v;
        #pragma unroll
        for (int j = 0; j < 8; ++j) {
            int k = kpc * 8 + j;
            unsigned short r = 0;
            if (k < 9) r = f2bf(sx[k / 3][px + (k % 3)]);
            else if (k == 9) r = (unsigned short)0x3F80;   // 1.0 multiplies bias row
            v[j] = (short)r;
        }
        int byte = (px * 64 + kpc * 16) ^ ((px & 7) << 4);
        *(short8*)((char*)sxa + byte) = v;
    }
    __syncthreads();

    const int l  = tid & 63;
    const int w  = tid >> 6;
    const int lc = l & 15;
    const int kp = l >> 4;
    const int gcol = w * 16 + lc;   // feature index 0..63

    floatx4 acc[4][4];
    #pragma unroll
    for (int m = 0; m < 4; ++m)
        #pragma unroll
        for (int q = 0; q < 4; ++q)
            acc[m][q] = (floatx4){0.f, 0.f, 0.f, 0.f};

    if (!FIRST) {
        // recurrent conv: 18 chunks, single-buffered (R4-proven structure)
        #pragma unroll
        for (int c = 0; c < 18; ++c) {
            const int tap_ = c >> 1, kc_ = c & 1, dy_ = tap_ / 3, dx_ = tap_ % 3;
            short8 af[4], bf[4];
            #pragma unroll
            for (int m_ = 0; m_ < 4; ++m_) {
                const int col_ = m_ * 16 + lc + dx_;
                int byte_ = ((dy_ * 66 + col_) * FF + kc_ * 32 + kp * 8) * 2;
                byte_ ^= ((col_ & 7) << 4);
                af[m_] = *(const short8*)(shb + byte_);
            }
            #pragma unroll
            for (int q_ = 0; q_ < 4; ++q_)
                bf[q_] = packedB[(size_t)(c * 16 + (q_ * 4 + w)) * 64 + l];
            #pragma unroll
            for (int m_ = 0; m_ < 4; ++m_)
                #pragma unroll
                for (int q_ = 0; q_ < 4; ++q_)
                    acc[m_][q_] = __builtin_amdgcn_mfma_f32_16x16x32_bf16(
                        af[m_], bf[q_], acc[m_][q_], 0, 0, 0);
        }
    }
    {
        // chunk 18: input conv + bias
        short8 af[4], bf[4];
        #pragma unroll
        for (int m_ = 0; m_ < 4; ++m_) {
            const int px_ = m_ * 16 + lc;
            int byte_ = (px_ * 64 + kp * 16) ^ ((px_ & 7) << 4);
            af[m_] = *(const short8*)((const char*)sxa + byte_);
        }
        #pragma unroll
        for (int q_ = 0; q_ < 4; ++q_)
            bf[q_] = packedB[(size_t)(18 * 16 + (q_ * 4 + w)) * 64 + l];
        #pragma unroll
        for (int m_ = 0; m_ < 4; ++m_)
            #pragma unroll
            for (int q_ = 0; q_ < 4; ++q_)
                acc[m_][q_] = __builtin_amdgcn_mfma_f32_16x16x32_bf16(
                    af[m_], bf[q_], acc[m_][q_], 0, 0, 0);
    }

    // epilogue: gates + cell update only (Keras order i,f,g,o)
    #pragma unroll
    for (int m = 0; m < 4; ++m) {
        #pragma unroll
        for (int r = 0; r < 4; ++r) {
            int p = m * 16 + kp * 4 + r;   // pixel within tile
            size_t idx = (((size_t)b * HH + y) * WW + (x0 + p)) * FF + gcol;
            float cp = FIRST ? 0.f : c_buf[idx];
            float iv = sigf(acc[m][0][r]);
            float fv = sigf(acc[m][1][r]);
            float gv = tanhfast(acc[m][2][r]);
            float ov = sigf(acc[m][3][r]);
            float cn = fv * cp + iv * gv;
            float hn = ov * tanhfast(cn);
            c_buf[idx] = cn;
            h_out[idx] = f2bf(hn);
        }
    }
}

// Fused decoder iteration:
//   pred = sigmoid(conv3x3(cur_in, w_out) + b_out)  -> out[:, ti]
//   cur_out = relu(pred * w_proj + b_proj)          (bf16)
__global__ __launch_bounds__(256) void dec_fused(
    const unsigned short* __restrict__ cur_in, const float* __restrict__ w_out,
    const float* __restrict__ b_out, const float* __restrict__ w_proj,
    const float* __restrict__ b_proj, float* __restrict__ out,
    unsigned short* __restrict__ cur_out, int ti)
{
    int tid = threadIdx.x;
    int j  = tid & 7;
    int pp = tid >> 3;
    int xx = blockIdx.x * 32 + pp;
    int y = blockIdx.y, b = blockIdx.z;

    float s = 0.f;
    for (int dy = 0; dy < 3; ++dy) {
        int gy = y + dy - 1;
        if ((unsigned)gy >= HH) continue;
        #pragma unroll
        for (int dx = 0; dx < 3; ++dx) {
            int gx = xx + dx - 1;
            if ((unsigned)gx >= WW) continue;
            const uint4 cv = *(const uint4*)(cur_in + ((((size_t)b * HH + gy) * WW + gx) * FF + j * 8));
            const float4* wp = (const float4*)&w_out[(dy * 3 + dx) * FF + j * 8];
            float4 w0 = wp[0], w1 = wp[1];
            unsigned cx = cv.x, cy = cv.y, cz = cv.z, cw = cv.w;
            s += __uint_as_float(cx << 16) * w0.x + __uint_as_float(cx & 0xFFFF0000u) * w0.y
               + __uint_as_float(cy << 16) * w0.z + __uint_as_float(cy & 0xFFFF0000u) * w0.w
               + __uint_as_float(cz << 16) * w1.x + __uint_as_float(cz & 0xFFFF0000u) * w1.y
               + __uint_as_float(cw << 16) * w1.z + __uint_as_float(cw & 0xFFFF0000u) * w1.w;
        }
    }
    s += __shfl_xor(s, 1);
    s += __shfl_xor(s, 2);
    s += __shfl_xor(s, 4);
    float pv = sigf(s + b_out[0]);

    size_t pix = (((size_t)b * HH + y) * WW + xx);
    if (j == 0)
        out[((size_t)b * PRED_LEN + ti) * (HH * WW) + (size_t)y * WW + xx] = pv;

    const float4* wp = (const float4*)w_proj;
    const float4* bp = (const float4*)b_proj;
    float4 w0 = wp[j * 2], w1 = wp[j * 2 + 1];
    float4 b0 = bp[j * 2], b1 = bp[j * 2 + 1];
    short8 o;
    o[0] = (short)f2bf(fmaxf(fmaf(pv, w0.x, b0.x), 0.f));
    o[1] = (short)f2bf(fmaxf(fmaf(pv, w0.y, b0.y), 0.f));
    o[2] = (short)f2bf(fmaxf(fmaf(pv, w0.z, b0.z), 0.f));
    o[3] = (short)f2bf(fmaxf(fmaf(pv, w0.w, b0.w), 0.f));
    o[4] = (short)f2bf(fmaxf(fmaf(pv, w1.x, b1.x), 0.f));
    o[5] = (short)f2bf(fmaxf(fmaf(pv, w1.y, b1.y), 0.f));
    o[6] = (short)f2bf(fmaxf(fmaf(pv, w1.z, b1.z), 0.f));
    o[7] = (short)f2bf(fmaxf(fmaf(pv, w1.w, b1.w), 0.f));
    *(short8*)(cur_out + pix * FF + j * 8) = o;
}

extern "C" void kernel_launch(void* const* d_in, const int* in_sizes, int n_in,
                              void* d_out, int out_size, void* d_ws, size_t ws_size,
                              hipStream_t stream)
{
    const float* x      = (const float*)d_in[0];
    const float* wk     = (const float*)d_in[1];
    const float* wr     = (const float*)d_in[2];
    const float* bias   = (const float*)d_in[3];
    const float* w_out  = (const float*)d_in[4];
    const float* b_out  = (const float*)d_in[5];
    const float* w_proj = (const float*)d_in[6];
    const float* b_proj = (const float*)d_in[7];
    float* out = (float*)d_out;

    const size_t SB = (size_t)BB * HH * WW * FF;   // 8388608 elems
    unsigned short* h_a = (unsigned short*)d_ws;
    unsigned short* h_b = h_a + SB;
    float* cb = (float*)((char*)d_ws + 2 * SB * sizeof(unsigned short));
    short8* packed = (short8*)((char*)cb + SB * sizeof(float));  // 19456*16 B

    pack_wr<<<76, 256, 0, stream>>>(wr, wk, bias, packed);

    dim3 gs(WW / TW, HH, BB);
    unsigned short* bufs[2] = {h_a, h_b};
    // FIRST writes every c/h element before any read -> no memset needed.
    lstm_step_mfma<true><<<gs, 256, 0, stream>>>(x, 0, bufs[0], cb, bufs[1], packed);
    for (int t = 1; t < TT; ++t) {
        lstm_step_mfma<false><<<gs, 256, 0, stream>>>(x, t, bufs[t & 1], cb,
                                                      bufs[(t + 1) & 1], packed);
    }

    for (int ti = 0; ti < PRED_LEN; ++ti) {
        dec_fused<<<dim3(WW / 32, HH, BB), 256, 0, stream>>>(
            bufs[ti & 1], w_out, b_out, w_proj, b_proj, out, bufs[(ti + 1) & 1], ti);
    }
}